// Round 18
// baseline (85.355 us; speedup 1.0000x reference)
//
#include <hip/hip_runtime.h>
#include <hip/hip_fp16.h>

#define P 10
#define D 1024
#define NROWS 16384

typedef float nfloat4 __attribute__((ext_vector_type(4)));   // clang-native for nontemporal builtins

// ---------------------------------------------------------------------------
// r17 keeper + ONE isolated change: masks 1,2 exchanged via DPP quad_perm
// (1:1 instruction swap, VALU pipe) instead of ds_swizzle. Masks 4,8,16,32
// stay __shfl_xor. DS ops/thread: 384 -> 256. DPP path was numerically
// verified in r12 (absmax 0.031); r12's regression came from the bundled
// permlane16/32 dual-select exchanges (VGPR 76->104), reverted here.
//
// Column mapping: k = e_hi*256 + lane*4 + e_lo, e in [0,16), lane in [0,64).
//   j=0,1 -> e bits (intra) | j=2..7 -> lane bit j-2 | j=8,9 -> e bits 2,3
// Coef: ctab[j*D + e*64 + lane] = uint2{h2(u),h2(v)}, f16, psi folded in j=9.
// ---------------------------------------------------------------------------
__global__ void coef_kernel(const float* __restrict__ theta,
                            const float* __restrict__ phi,
                            const float* __restrict__ psi,
                            uint2* __restrict__ ctab) {
    int idx = blockIdx.x * blockDim.x + threadIdx.x;
    if (idx >= P * D) return;
    int j = idx >> 10;
    int slot = idx & (D - 1);
    int e = slot >> 6;
    int lane = slot & 63;
    int k = ((e >> 2) << 8) + (lane << 2) + (e & 3);   // column this slot serves
    int b = (k >> j) & 1;
    unsigned lowmask = (1u << j) - 1u;
    unsigned m = ((unsigned)k & lowmask) | (((unsigned)k >> 1) & ~lowmask); // delete bit j
    float th = theta[j * (D / 2) + m];
    float ph = phi[j * (D / 2) + m];
    float h = th * 0.5f;
    float s1 = sinf(h), c1 = cosf(h);
    float s2 = sinf(h + ph), c2 = cosf(h + ph);
    float ur, ui, vr, vi;
    if (b) { ur =  s1 * s1; vr = -c1 * s2; ui = -c1 * s1; vi = c1 * c2; }
    else   { ur = -s1 * s2; vr = -c1 * s1; ui =  s1 * c2; vi = c1 * c1; }
    if (j == P - 1) {
        float ps = psi[k];
        float cp = cosf(ps), sp = sinf(ps);
        float ur2 = cp * ur - sp * ui, ui2 = sp * ur + cp * ui;
        float vr2 = cp * vr - sp * vi, vi2 = sp * vr + cp * vi;
        ur = ur2; ui = ui2; vr = vr2; vi = vi2;
    }
    __half2 uh = __floats2half2_rn(ur, ui);
    __half2 vh = __floats2half2_rn(vr, vi);
    uint2 w;
    w.x = *reinterpret_cast<unsigned int*>(&uh);
    w.y = *reinterpret_cast<unsigned int*>(&vh);
    ctab[idx] = w;
}

__device__ __forceinline__ void unpack_c(uint2 w, float& ur, float& ui,
                                         float& vr, float& vi) {
    __half2 a = *reinterpret_cast<__half2*>(&w.x);
    __half2 b = *reinterpret_cast<__half2*>(&w.y);
    ur = __low2float(a); ui = __high2float(a);
    vr = __low2float(b); vi = __high2float(b);
}

// DPP quad_perm XOR exchange (verified correct in r12): 1 VALU op, no DS.
template <int CTRL>
__device__ __forceinline__ float xdpp(float x) {
    return __uint_as_float((unsigned)__builtin_amdgcn_update_dpp(
        0, (int)__float_as_uint(x), CTRL, 0xF, 0xF, true));
}

template <int MASK>
__device__ __forceinline__ float lane_xor(float x) {
    if constexpr (MASK == 1) return xdpp<0xB1>(x);   // quad_perm [1,0,3,2]
    else if constexpr (MASK == 2) return xdpp<0x4E>(x); // quad_perm [2,3,0,1]
    else return __shfl_xor(x, MASK);
}

// ---------------------------------------------------------------------------
// Intra-thread butterfly stage: partner differs in a bit of e (mask PM).
// ---------------------------------------------------------------------------
template <int PM>
__device__ __forceinline__ void stage_intra(float (&ra)[16], float (&ia)[16],
                                            float (&rb)[16], float (&ib)[16],
                                            const uint2* cj) {
#pragma unroll
    for (int e0 = 0; e0 < 16; ++e0) {
        if (e0 & PM) continue;
        const int e1 = e0 | PM;
        uint2 w0 = cj[e0 * 64];
        uint2 w1 = cj[e1 * 64];
        float u0r, u0i, v0r, v0i, u1r, u1i, v1r, v1i;
        unpack_c(w0, u0r, u0i, v0r, v0i);
        unpack_c(w1, u1r, u1i, v1r, v1i);
        float ar0 = ra[e0], ai0 = ia[e0], ar1 = ra[e1], ai1 = ia[e1];
        float br0 = rb[e0], bi0 = ib[e0], br1 = rb[e1], bi1 = ib[e1];
        ra[e0] = u0r * ar0 - u0i * ai0 + v0r * ar1 - v0i * ai1;
        ia[e0] = u0r * ai0 + u0i * ar0 + v0r * ai1 + v0i * ar1;
        ra[e1] = u1r * ar1 - u1i * ai1 + v1r * ar0 - v1i * ai0;
        ia[e1] = u1r * ai1 + u1i * ar1 + v1r * ai0 + v1i * ar0;
        rb[e0] = u0r * br0 - u0i * bi0 + v0r * br1 - v0i * bi1;
        ib[e0] = u0r * bi0 + u0i * br0 + v0r * bi1 + v0i * br1;
        rb[e1] = u1r * br1 - u1i * bi1 + v1r * br0 - v1i * bi0;
        ib[e1] = u1r * bi1 + u1i * br1 + v1r * bi0 + v1i * br0;
    }
}

// ---------------------------------------------------------------------------
// Cross-lane butterfly stage: partner differs in lane bit MASK.
// ---------------------------------------------------------------------------
template <int MASK>
__device__ __forceinline__ void stage_shfl(float (&ra)[16], float (&ia)[16],
                                           float (&rb)[16], float (&ib)[16],
                                           const uint2* cj) {
#pragma unroll
    for (int e = 0; e < 16; ++e) {
        uint2 w = cj[e * 64];
        float ur, ui, vr, vi;
        unpack_c(w, ur, ui, vr, vi);
        float sra = lane_xor<MASK>(ra[e]);
        float sia = lane_xor<MASK>(ia[e]);
        float srb = lane_xor<MASK>(rb[e]);
        float sib = lane_xor<MASK>(ib[e]);
        float nra = ur * ra[e] - ui * ia[e] + vr * sra - vi * sia;
        float nia = ur * ia[e] + ui * ra[e] + vr * sia + vi * sra;
        float nrb = ur * rb[e] - ui * ib[e] + vr * srb - vi * sib;
        float nib = ur * ib[e] + ui * rb[e] + vr * sib + vi * srb;
        ra[e] = nra; ia[e] = nia; rb[e] = nrb; ib[e] = nib;
    }
}

__global__ __launch_bounds__(256) void fft_kernel(const float* __restrict__ X,
                                                  const uint2* __restrict__ ctab,
                                                  float* __restrict__ out) {
    const int lane = threadIdx.x & 63;
    const int wave = threadIdx.x >> 6;
    const long rowbase = (long)blockIdx.x * 8 + (long)wave * 2;
    const float* x0 = X + rowbase * 2048 + lane * 4;
    const float* x1 = x0 + 2048;
    const uint2* cb = ctab + lane;

    float ra[16], ia[16], rb[16], ib[16];
#pragma unroll
    for (int eh = 0; eh < 4; ++eh) {
        float4 v0r = *(const float4*)(x0 + eh * 256);
        float4 v0i = *(const float4*)(x0 + 1024 + eh * 256);
        float4 v1r = *(const float4*)(x1 + eh * 256);
        float4 v1i = *(const float4*)(x1 + 1024 + eh * 256);
        ra[eh * 4 + 0] = v0r.x; ra[eh * 4 + 1] = v0r.y; ra[eh * 4 + 2] = v0r.z; ra[eh * 4 + 3] = v0r.w;
        ia[eh * 4 + 0] = v0i.x; ia[eh * 4 + 1] = v0i.y; ia[eh * 4 + 2] = v0i.z; ia[eh * 4 + 3] = v0i.w;
        rb[eh * 4 + 0] = v1r.x; rb[eh * 4 + 1] = v1r.y; rb[eh * 4 + 2] = v1r.z; rb[eh * 4 + 3] = v1r.w;
        ib[eh * 4 + 0] = v1i.x; ib[eh * 4 + 1] = v1i.y; ib[eh * 4 + 2] = v1i.z; ib[eh * 4 + 3] = v1i.w;
    }

    stage_intra<1>(ra, ia, rb, ib, cb + 0 * D);
    stage_intra<2>(ra, ia, rb, ib, cb + 1 * D);

    stage_shfl<1>(ra, ia, rb, ib, cb + 2 * D);    // DPP
    stage_shfl<2>(ra, ia, rb, ib, cb + 3 * D);    // DPP
    stage_shfl<4>(ra, ia, rb, ib, cb + 4 * D);    // ds_swizzle
    stage_shfl<8>(ra, ia, rb, ib, cb + 5 * D);    // ds_swizzle
    stage_shfl<16>(ra, ia, rb, ib, cb + 6 * D);   // ds_swizzle
    stage_shfl<32>(ra, ia, rb, ib, cb + 7 * D);   // ds_swizzle

    stage_intra<4>(ra, ia, rb, ib, cb + 8 * D);
    stage_intra<8>(ra, ia, rb, ib, cb + 9 * D);

    float* o0 = out + rowbase * 2048 + lane * 4;
    float* o1 = o0 + 2048;
#pragma unroll
    for (int eh = 0; eh < 4; ++eh) {
        nfloat4 v0r = { ra[eh * 4 + 0], ra[eh * 4 + 1], ra[eh * 4 + 2], ra[eh * 4 + 3] };
        nfloat4 v0i = { ia[eh * 4 + 0], ia[eh * 4 + 1], ia[eh * 4 + 2], ia[eh * 4 + 3] };
        nfloat4 v1r = { rb[eh * 4 + 0], rb[eh * 4 + 1], rb[eh * 4 + 2], rb[eh * 4 + 3] };
        nfloat4 v1i = { ib[eh * 4 + 0], ib[eh * 4 + 1], ib[eh * 4 + 2], ib[eh * 4 + 3] };
        __builtin_nontemporal_store(v0r, (nfloat4*)(o0 + eh * 256));
        __builtin_nontemporal_store(v0i, (nfloat4*)(o0 + 1024 + eh * 256));
        __builtin_nontemporal_store(v1r, (nfloat4*)(o1 + eh * 256));
        __builtin_nontemporal_store(v1i, (nfloat4*)(o1 + 1024 + eh * 256));
    }
}

extern "C" void kernel_launch(void* const* d_in, const int* in_sizes, int n_in,
                              void* d_out, int out_size, void* d_ws, size_t ws_size,
                              hipStream_t stream) {
    const float* X     = (const float*)d_in[0];
    const float* theta = (const float*)d_in[1];
    const float* phi   = (const float*)d_in[2];
    const float* psi   = (const float*)d_in[3];
    uint2* ctab = (uint2*)d_ws;   // P*D*8 B = 80 KB

    coef_kernel<<<(P * D + 255) / 256, 256, 0, stream>>>(theta, phi, psi, ctab);
    fft_kernel<<<NROWS / 8, 256, 0, stream>>>(X, ctab, (float*)d_out);
}